// Round 1
// baseline (214.067 us; speedup 1.0000x reference)
//
#include <hip/hip_runtime.h>
#include <hip/hip_bf16.h>

typedef short bf8 __attribute__((ext_vector_type(8)));   // 8 bf16 values (4 VGPRs)
typedef float f4 __attribute__((ext_vector_type(4)));

#define S_LEN 4096
#define H_DIM 1024
#define D_DIM 512
#define B_DIM 16
#define BK 64
#define PAD 8

// float -> bf16 bits with round-to-nearest-even
static __device__ __forceinline__ unsigned short f2bf(float f) {
    union { float f; unsigned int u; } c; c.f = f;
    unsigned int u = c.u;
    unsigned int r = (u + 0x7FFFu + ((u >> 16) & 1u)) >> 16;
    return (unsigned short)r;
}

// cW1 [K=1024][N=512] f32 row-major  ->  wT [N=512][K=1024] bf16
__global__ __launch_bounds__(256) void prep_transpose(const float* __restrict__ cW1,
                                                      unsigned short* __restrict__ wT) {
    __shared__ float tile[64][68];
    const int kt = blockIdx.x >> 3;   // 16 k-tiles of 64
    const int nt = blockIdx.x & 7;    // 8 n-tiles of 64
    const int tr = threadIdx.x >> 4;  // 0..15
    const int tc = threadIdx.x & 15;  // 0..15
#pragma unroll
    for (int i = 0; i < 4; ++i) {
        const float4 v = *(const float4*)(cW1 + (size_t)(kt * 64 + i * 16 + tr) * D_DIM + nt * 64 + tc * 4);
        tile[i * 16 + tr][tc * 4 + 0] = v.x;
        tile[i * 16 + tr][tc * 4 + 1] = v.y;
        tile[i * 16 + tr][tc * 4 + 2] = v.z;
        tile[i * 16 + tr][tc * 4 + 3] = v.w;
    }
    __syncthreads();
#pragma unroll
    for (int i = 0; i < 4; ++i) {
        const int n = i * 16 + tr;
        ushort4 o;
        o.x = f2bf(tile[tc * 4 + 0][n]);
        o.y = f2bf(tile[tc * 4 + 1][n]);
        o.z = f2bf(tile[tc * 4 + 2][n]);
        o.w = f2bf(tile[tc * 4 + 3][n]);
        *(ushort4*)(wT + (size_t)(nt * 64 + n) * H_DIM + kt * 64 + tc * 4) = o;
    }
}

// steps_used ≡ 1 (structurally guaranteed: rb<=128-t can never make trunc(rb/(S-t+1))>=2,
// and negative rb clips to MIN_STEPS=1), rb_final = 128 - 4096 = -3968.
__global__ __launch_bounds__(256) void write_consts(float* __restrict__ out) {
    const size_t steps_off = (size_t)B_DIM * S_LEN * H_DIM;
    const int i = blockIdx.x * 256 + threadIdx.x;
    if (i < S_LEN) out[steps_off + i] = 1.0f;
    if (i == 0) out[steps_off + 2 * S_LEN] = -3968.0f;
}

// Fused: states copy -> d_out  +  comp_mean[s] = mean_b sigmoid(relu(states@cW1+cb1)@cW2+cb2)
// Block: 8 s-values x 16 b = 128 rows, full N=512, K-loop BK=64. 8 waves = 2(M) x 4(N).
__global__ __launch_bounds__(512, 2) void fused_gemm_kernel(
    const float* __restrict__ states,
    const unsigned short* __restrict__ wT,
    const float* __restrict__ cb1,
    const float* __restrict__ cW2,
    const float* __restrict__ cb2,
    float* __restrict__ out) {
    __shared__ unsigned short As[128][BK + PAD];   // 18 KB
    __shared__ unsigned short Bs[D_DIM][BK + PAD]; // 72 KB
    __shared__ float part[8][16][4];               // [j][b][wn]

    const int t = threadIdx.x;
    const int lane = t & 63;
    const int w = t >> 6;
    const int wm = w >> 2;   // 0..1 : rows [wm*64, +64)
    const int wn = w & 3;    // 0..3 : cols [wn*128, +128)
    const int s0 = blockIdx.x * 8;

    f4 acc[4][8];
#pragma unroll
    for (int a = 0; a < 4; ++a)
#pragma unroll
        for (int b = 0; b < 8; ++b) acc[a][b] = f4{0.f, 0.f, 0.f, 0.f};

    for (int ck = 0; ck < 16; ++ck) {
        const int k0 = ck * BK;
        // ---- stage A (f32 -> bf16), fused copy of states to d_out ----
#pragma unroll
        for (int ii = 0; ii < 2; ++ii) {
            const int seg = t + ii * 512;       // 1024 segments of 8 floats
            const int r = seg >> 3;             // tile row 0..127  (r = j*16 + b)
            const int ks = seg & 7;
            const int bb = r & 15;
            const int jj = r >> 4;
            const size_t g = ((size_t)bb * S_LEN + s0 + jj) * H_DIM + k0 + ks * 8;
            const float4 v0 = *(const float4*)(states + g);
            const float4 v1 = *(const float4*)(states + g + 4);
            *(float4*)(out + g) = v0;           // output 0 = states (each elem exactly once)
            *(float4*)(out + g + 4) = v1;
            bf8 av;
            av[0] = (short)f2bf(v0.x); av[1] = (short)f2bf(v0.y);
            av[2] = (short)f2bf(v0.z); av[3] = (short)f2bf(v0.w);
            av[4] = (short)f2bf(v1.x); av[5] = (short)f2bf(v1.y);
            av[6] = (short)f2bf(v1.z); av[7] = (short)f2bf(v1.w);
            *(bf8*)&As[r][ks * 8] = av;
        }
        // ---- stage B from wT (bf16, [n][k]) ----
#pragma unroll
        for (int pp = 0; pp < 8; ++pp) {
            const int n = pp * 64 + (t >> 3);
            const int ks = t & 7;
            const bf8 v = *(const bf8*)(wT + (size_t)n * H_DIM + k0 + ks * 8);
            *(bf8*)&Bs[n][ks * 8] = v;
        }
        __syncthreads();
        // ---- MFMA: 2 k-steps of 32 ----
#pragma unroll
        for (int kk = 0; kk < 2; ++kk) {
            bf8 af[4], bfr[8];
            const int kb = kk * 32 + (lane >> 4) * 8;
            const int la = lane & 15;
#pragma unroll
            for (int fr = 0; fr < 4; ++fr)
                af[fr] = *(const bf8*)&As[wm * 64 + fr * 16 + la][kb];
#pragma unroll
            for (int fc = 0; fc < 8; ++fc)
                bfr[fc] = *(const bf8*)&Bs[wn * 128 + fc * 16 + la][kb];
#pragma unroll
            for (int fr = 0; fr < 4; ++fr)
#pragma unroll
                for (int fc = 0; fc < 8; ++fc)
                    acc[fr][fc] = __builtin_amdgcn_mfma_f32_16x16x32_bf16(af[fr], bfr[fc], acc[fr][fc], 0, 0, 0);
        }
        __syncthreads();
    }

    // ---- epilogue: relu + dot(cW2) + sigmoid + mean over b ----
    const int la = lane & 15;   // C col within fragment (hidden dim)
    const int lg = lane >> 4;   // C row group
    float w2v[8], b1v[8];
#pragma unroll
    for (int fc = 0; fc < 8; ++fc) {
        const int d = wn * 128 + fc * 16 + la;
        w2v[fc] = cW2[d];
        b1v[fc] = cb1[d];
    }
#pragma unroll
    for (int fr = 0; fr < 4; ++fr) {
#pragma unroll
        for (int rg = 0; rg < 4; ++rg) {
            float p = 0.f;
#pragma unroll
            for (int fc = 0; fc < 8; ++fc) {
                const float h = acc[fr][fc][rg] + b1v[fc];
                p += fmaxf(h, 0.f) * w2v[fc];
            }
            // sum over the 16 lane-columns (hidden dims) of this wave
#pragma unroll
            for (int off = 1; off < 16; off <<= 1)
                p += __shfl_xor(p, off, 64);
            if (la == 0) part[wm * 4 + fr][lg * 4 + rg][wn] = p;
        }
    }
    __syncthreads();
    if (t < 128) {
        const int j = t >> 4;   // s offset 0..7
        const int b = t & 15;
        const float sum = part[j][b][0] + part[j][b][1] + part[j][b][2] + part[j][b][3] + cb2[0];
        float sg = 1.f / (1.f + __expf(-sum));
#pragma unroll
        for (int off = 1; off < 16; off <<= 1)
            sg += __shfl_xor(sg, off, 64);  // mean over b
        if (b == 0)
            out[(size_t)B_DIM * S_LEN * H_DIM + S_LEN + s0 + j] = sg * (1.f / 16.f);
    }
}

extern "C" void kernel_launch(void* const* d_in, const int* in_sizes, int n_in,
                              void* d_out, int out_size, void* d_ws, size_t ws_size,
                              hipStream_t stream) {
    const float* states = (const float*)d_in[0];
    const float* cW1 = (const float*)d_in[5];
    const float* cb1 = (const float*)d_in[6];
    const float* cW2 = (const float*)d_in[7];
    const float* cb2 = (const float*)d_in[8];
    float* out = (float*)d_out;
    unsigned short* wT = (unsigned short*)d_ws;  // 512*1024 bf16 = 1 MB

    hipLaunchKernelGGL(prep_transpose, dim3(128), dim3(256), 0, stream, cW1, wT);
    hipLaunchKernelGGL(write_consts, dim3(16), dim3(256), 0, stream, out);
    hipLaunchKernelGGL(fused_gemm_kernel, dim3(512), dim3(512), 0, stream,
                       states, wT, cb1, cW2, cb2, out);
}